// Round 1
// baseline (567.319 us; speedup 1.0000x reference)
//
#include <hip/hip_runtime.h>

#define NUM_CLASSES 19

// One workgroup per 32x32 tile of `targets`.
// Phase 1: 256 threads x int4 load = 1024 labels -> presence bitmask in LDS.
// Phase 2: wave 0 lanes 0..18 compute BCE(sigmoid(preds), presence) terms,
//          shuffle-reduce, one atomicAdd of blocksum/total into d_out.
__global__ __launch_bounds__(256) void seg_encode_loss_kernel(
    const float* __restrict__ preds,
    const int*   __restrict__ targets,
    float*       __restrict__ out,
    float inv_total)
{
    const int n = blockIdx.x;      // tile index 0..32767 : n = b*1024 + by*32 + bx
    const int t = threadIdx.x;     // 0..255

    const int b  = n >> 10;
    const int by = (n >> 5) & 31;
    const int bx = n & 31;

    // element offset of tile origin in [32,1024,1024]
    const long long base = (long long)b * (1024 * 1024)
                         + (long long)(by * 32) * 1024
                         + (long long)(bx * 32);

    const int row  = t >> 3;   // 0..31
    const int quad = t & 7;    // 0..7 (4 ints each; 16B-aligned)

    const int4 v = *(const int4*)(targets + base + (long long)row * 1024 + quad * 4);

    // labels are in [0, NUM_CLASSES) < 32, so a 32-bit mask suffices
    unsigned mask = (1u << v.x) | (1u << v.y) | (1u << v.z) | (1u << v.w);

    // 64-lane OR butterfly
    mask |= __shfl_xor(mask, 1);
    mask |= __shfl_xor(mask, 2);
    mask |= __shfl_xor(mask, 4);
    mask |= __shfl_xor(mask, 8);
    mask |= __shfl_xor(mask, 16);
    mask |= __shfl_xor(mask, 32);

    __shared__ unsigned smask;
    if (t == 0) smask = 0u;
    __syncthreads();
    if ((t & 63) == 0) atomicOr(&smask, mask);
    __syncthreads();

    if (t < 64) {
        const unsigned m = smask;
        float loss = 0.0f;
        if (t < NUM_CLASSES) {
            const float x  = preds[n * NUM_CLASSES + t];
            const float tv = ((m >> t) & 1u) ? 1.0f : 0.0f;
            // stable: loss = softplus(x) - t*x ;  softplus(x)=max(x,0)+log1p(exp(-|x|))
            const float sp = fmaxf(x, 0.0f) + log1pf(__expf(-fabsf(x)));
            loss = sp - tv * x;
        }
        loss += __shfl_xor(loss, 1);
        loss += __shfl_xor(loss, 2);
        loss += __shfl_xor(loss, 4);
        loss += __shfl_xor(loss, 8);
        loss += __shfl_xor(loss, 16);
        loss += __shfl_xor(loss, 32);
        if (t == 0) atomicAdd(out, loss * inv_total);
    }
}

extern "C" void kernel_launch(void* const* d_in, const int* in_sizes, int n_in,
                              void* d_out, int out_size, void* d_ws, size_t ws_size,
                              hipStream_t stream) {
    const float* preds   = (const float*)d_in[0];
    const int*   targets = (const int*)d_in[1];
    float*       out     = (float*)d_out;

    const int n_tiles = in_sizes[0] / NUM_CLASSES;  // 32768
    const float inv_total = 1.0f / (float)(n_tiles * NUM_CLASSES);

    // d_out is poisoned with 0xAA before every timed replay — zero it first.
    hipMemsetAsync(out, 0, sizeof(float), stream);

    seg_encode_loss_kernel<<<n_tiles, 256, 0, stream>>>(preds, targets, out, inv_total);
}

// Round 2
// 199.260 us; speedup vs baseline: 2.8471x; 2.8471x over previous
//
#include <hip/hip_runtime.h>

#define NUM_CLASSES 19
#define TILES_PER_WAVE 8
#define WAVES_PER_BLOCK 4
// 32768 tiles / (8 tiles/wave * 4 waves/block) = 1024 blocks

// Each 64-lane wave processes TILES_PER_WAVE whole 32x32 tiles:
// per tile, 64 lanes x 4 int4 = 1024 labels -> OR-butterfly -> presence mask
// (no LDS, no barrier). Lanes 0..18 accumulate BCE terms across their tiles.
// One partial sum per block written to d_ws; no global atomics.
__global__ __launch_bounds__(256) void seg_loss_partial(
    const float* __restrict__ preds,
    const int*   __restrict__ targets,
    float*       __restrict__ partial)
{
    const int t    = threadIdx.x;
    const int wave = t >> 6;
    const int lane = t & 63;

    float loss = 0.0f;
    const int tile0 = (blockIdx.x * WAVES_PER_BLOCK + wave) * TILES_PER_WAVE;

    for (int i = 0; i < TILES_PER_WAVE; ++i) {
        const int n  = tile0 + i;               // tile = b*1024 + by*32 + bx
        const int b  = n >> 10;
        const int by = (n >> 5) & 31;
        const int bx = n & 31;
        const int* base = targets + ((long long)b << 20)
                                  + (long long)(by << 5) * 1024
                                  + (bx << 5);

        unsigned mask = 0u;
        #pragma unroll
        for (int j = 0; j < 4; ++j) {
            const int idx  = j * 64 + lane;     // int4 index within tile, 0..255
            const int row  = idx >> 3;          // 0..31
            const int quad = idx & 7;           // 0..7
            const int4 v = *(const int4*)(base + row * 1024 + quad * 4);
            mask |= (1u << v.x) | (1u << v.y) | (1u << v.z) | (1u << v.w);
        }

        // 64-lane OR butterfly
        mask |= __shfl_xor(mask, 1);
        mask |= __shfl_xor(mask, 2);
        mask |= __shfl_xor(mask, 4);
        mask |= __shfl_xor(mask, 8);
        mask |= __shfl_xor(mask, 16);
        mask |= __shfl_xor(mask, 32);

        if (lane < NUM_CLASSES) {
            const float x  = preds[n * NUM_CLASSES + lane];
            const float tv = ((mask >> lane) & 1u) ? 1.0f : 0.0f;
            // stable BCE term: softplus(x) - t*x
            const float sp = fmaxf(x, 0.0f) + log1pf(__expf(-fabsf(x)));
            loss += sp - tv * x;
        }
    }

    // wave-level sum
    loss += __shfl_xor(loss, 1);
    loss += __shfl_xor(loss, 2);
    loss += __shfl_xor(loss, 4);
    loss += __shfl_xor(loss, 8);
    loss += __shfl_xor(loss, 16);
    loss += __shfl_xor(loss, 32);

    __shared__ float wsum[WAVES_PER_BLOCK];
    if (lane == 0) wsum[wave] = loss;
    __syncthreads();
    if (t == 0)
        partial[blockIdx.x] = wsum[0] + wsum[1] + wsum[2] + wsum[3];
}

__global__ __launch_bounds__(256) void seg_loss_reduce(
    const float* __restrict__ partial,
    float*       __restrict__ out,
    float inv_total, int n)
{
    float s = 0.0f;
    for (int i = threadIdx.x; i < n; i += 256) s += partial[i];

    s += __shfl_xor(s, 1);
    s += __shfl_xor(s, 2);
    s += __shfl_xor(s, 4);
    s += __shfl_xor(s, 8);
    s += __shfl_xor(s, 16);
    s += __shfl_xor(s, 32);

    __shared__ float wsum[4];
    const int wave = threadIdx.x >> 6;
    const int lane = threadIdx.x & 63;
    if (lane == 0) wsum[wave] = s;
    __syncthreads();
    if (threadIdx.x == 0)
        out[0] = (wsum[0] + wsum[1] + wsum[2] + wsum[3]) * inv_total;
}

extern "C" void kernel_launch(void* const* d_in, const int* in_sizes, int n_in,
                              void* d_out, int out_size, void* d_ws, size_t ws_size,
                              hipStream_t stream) {
    const float* preds   = (const float*)d_in[0];
    const int*   targets = (const int*)d_in[1];
    float*       out     = (float*)d_out;
    float*       partial = (float*)d_ws;

    const int n_tiles  = in_sizes[0] / NUM_CLASSES;                  // 32768
    const int n_blocks = n_tiles / (TILES_PER_WAVE * WAVES_PER_BLOCK); // 1024
    const float inv_total = 1.0f / (float)(n_tiles * NUM_CLASSES);

    seg_loss_partial<<<n_blocks, 256, 0, stream>>>(preds, targets, partial);
    seg_loss_reduce<<<1, 256, 0, stream>>>(partial, out, inv_total, n_blocks);
}